// Round 3
// baseline (268.534 us; speedup 1.0000x reference)
//
#include <hip/hip_runtime.h>
#include <cstdint>
#include <cstddef>

namespace {

constexpr int NCLS   = 32;
constexpr int KSHOT  = 5;
constexpr int FDIM   = 21168;   // 3*84*84
constexpr int KPAD   = 21248;   // 664 * 32
constexpr int DDIM   = 1600;
constexpr int NROW   = 512;     // 32 proto + 480 query
constexpr int NQROW  = 480;
constexpr int NKT2   = 664;     // K tiles of 32
constexpr int MAXS   = 9;       // split-K: grid = 26*9 = 234 <= 256 CUs

using short8 = __attribute__((ext_vector_type(8))) short;
using f32x4  = __attribute__((ext_vector_type(4))) float;

__device__ __forceinline__ unsigned f2bf(float x) {
    union { float f; unsigned u; } v; v.f = x;
    unsigned r = v.u + 0x7fffu + ((v.u >> 16) & 1u);   // RNE
    return r >> 16;
}

// ---------------------------------------------------------------------------
// Kernel 1: build A_bf16 [512][KPAD]; rows 0..31 = 5-shot mean, rest = query.
// 2D grid: y = row, x covers KPAD/4 float4 units (no per-element division).
// ---------------------------------------------------------------------------
__global__ void prep_A(const float* __restrict__ supp,
                       const float* __restrict__ query,
                       unsigned short* __restrict__ A) {
    const int r = blockIdx.y;
    const int u = blockIdx.x * blockDim.x + threadIdx.x;
    if (u >= KPAD / 4) return;
    const int c = u * 4;
    float4 v = make_float4(0.f, 0.f, 0.f, 0.f);
    if (c < FDIM) {   // FDIM % 4 == 0 -> full vec in range
        if (r < NCLS) {
            const float* s = supp + (size_t)r * KSHOT * FDIM + c;
            float4 a0 = *(const float4*)(s);
            float4 a1 = *(const float4*)(s + FDIM);
            float4 a2 = *(const float4*)(s + 2 * FDIM);
            float4 a3 = *(const float4*)(s + 3 * FDIM);
            float4 a4 = *(const float4*)(s + 4 * FDIM);
            v.x = (a0.x + a1.x + a2.x + a3.x + a4.x) * 0.2f;
            v.y = (a0.y + a1.y + a2.y + a3.y + a4.y) * 0.2f;
            v.z = (a0.z + a1.z + a2.z + a3.z + a4.z) * 0.2f;
            v.w = (a0.w + a1.w + a2.w + a3.w + a4.w) * 0.2f;
        } else {
            v = *(const float4*)(query + (size_t)(r - NCLS) * FDIM + c);
        }
    }
    ushort4 o;
    o.x = (unsigned short)f2bf(v.x); o.y = (unsigned short)f2bf(v.y);
    o.z = (unsigned short)f2bf(v.z); o.w = (unsigned short)f2bf(v.w);
    *(ushort4*)(A + (size_t)r * KPAD + c) = o;
}

// ---------------------------------------------------------------------------
// Kernel 2: GEMM Cpart[s] = A[BM-range][K-range] @ bf16(W[K-range][BN-range])
// 1024 threads = 16 waves (4m x 4n), wave tile 64x32, BM=256 BN=128 BK=32.
// Pipeline: at tile t issue A(t+1)->regs and W(t+2)->regs; the tile-end
// __syncthreads() (vmcnt0) is the drain, so next tile's pack/MFMA never
// waits on VMEM. B: bf16 pack + ds_write_b64 with 8B XOR swizzle.
// ---------------------------------------------------------------------------
__global__ __launch_bounds__(1024, 4) void gemm3(
        const unsigned short* __restrict__ A,   // [512][KPAD] bf16 bits
        const float* __restrict__ W,            // [FDIM][DDIM] fp32
        float* __restrict__ Cpart, int S) {     // [S][512][DDIM]
    __shared__ unsigned short Blds[2][128 * 32];   // 8 KB each half

    const int bid = blockIdx.x;
    const int s   = bid / 26;
    const int rem = bid % 26;
    const int mt  = rem / 13;
    const int nt  = rem % 13;
    const int m0  = mt * 256;
    const int n0  = nt * 128;
    const int t0  = (NKT2 * s) / S;
    const int t1  = (NKT2 * (s + 1)) / S;

    const int tid  = threadIdx.x;
    const int lane = tid & 63;
    const int wid  = tid >> 6;       // 0..15
    const int wr   = wid & 3;        // m-wave
    const int wc   = wid >> 2;       // n-wave
    const int g    = lane >> 4;      // k sub-block 0..3
    const int r15  = lane & 15;

    // B staging: every thread stages 4 k-consecutive elems of one column
    const int bn = tid & 127;        // column 0..127
    const int kq = tid >> 7;         // k-quad 0..7
    const int ncol = n0 + bn;
    const bool nok = ncol < DDIM;
    const float* Wp = W + (nok ? ncol : 0);
    const int wsw = (kq ^ ((bn >> 1) & 7)) * 4;   // swizzled k-quad (shorts)

    // per-lane A row pointers (loop-invariant, include g*8 k-offset)
    const unsigned short* Arow[4];
    #pragma unroll
    for (int ms = 0; ms < 4; ++ms)
        Arow[ms] = A + (size_t)(m0 + wr * 64 + ms * 16 + r15) * KPAD + g * 8;

    f32x4 acc[4][2];
    #pragma unroll
    for (int i = 0; i < 4; ++i)
        #pragma unroll
        for (int j = 0; j < 2; ++j)
            acc[i][j] = (f32x4){0.f, 0.f, 0.f, 0.f};

    float wv0[4], wvC[4], wvN[4];
    short8 afC[4], afN[4];

    // --- prologue: B(t0) via wv0; issue W(t0+1), A(t0) ---
    {
        const int k0 = t0 * 32;
        #pragma unroll
        for (int i = 0; i < 4; ++i) {
            const int k = k0 + kq * 4 + i;
            wv0[i] = (nok && k < FDIM) ? Wp[(size_t)k * DDIM] : 0.f;
        }
    }
    if (t0 + 1 < t1) {
        const int k0 = (t0 + 1) * 32;
        #pragma unroll
        for (int i = 0; i < 4; ++i) {
            const int k = k0 + kq * 4 + i;
            wvC[i] = (nok && k < FDIM) ? Wp[(size_t)k * DDIM] : 0.f;
        }
    } else {
        #pragma unroll
        for (int i = 0; i < 4; ++i) wvC[i] = 0.f;
    }
    #pragma unroll
    for (int ms = 0; ms < 4; ++ms)
        afC[ms] = *(const short8*)(Arow[ms] + t0 * 32);
    {
        uint2 p;
        p.x = f2bf(wv0[0]) | (f2bf(wv0[1]) << 16);
        p.y = f2bf(wv0[2]) | (f2bf(wv0[3]) << 16);
        *(uint2*)&Blds[0][bn * 32 + wsw] = p;
    }
    __syncthreads();

    int c = 0;
    for (int t = t0; t < t1; ++t) {
        const bool m1 = (t + 1 < t1);
        const bool m2 = (t + 2 < t1);
        // issue next-next W and next A first (drained at this tile's barrier)
        if (m2) {
            const int k0 = (t + 2) * 32;
            #pragma unroll
            for (int i = 0; i < 4; ++i) {
                const int k = k0 + kq * 4 + i;
                wvN[i] = (nok && k < FDIM) ? Wp[(size_t)k * DDIM] : 0.f;
            }
        }
        if (m1) {
            #pragma unroll
            for (int ms = 0; ms < 4; ++ms)
                afN[ms] = *(const short8*)(Arow[ms] + (t + 1) * 32);
            // pack B(t+1) from wvC (already arrived: drained last barrier)
            uint2 p;
            p.x = f2bf(wvC[0]) | (f2bf(wvC[1]) << 16);
            p.y = f2bf(wvC[2]) | (f2bf(wvC[3]) << 16);
            *(uint2*)&Blds[c ^ 1][bn * 32 + wsw] = p;
        }
        // compute on Blds[c] with afC
        #pragma unroll
        for (int ns = 0; ns < 2; ++ns) {
            const int n = wc * 32 + ns * 16 + r15;
            const int base = n * 32;
            const int sw = (n >> 1) & 7;
            short8 bf;
            *(uint2*)&bf       = *(const uint2*)&Blds[c][base + ((g * 2 + 0) ^ sw) * 4];
            *((uint2*)&bf + 1) = *(const uint2*)&Blds[c][base + ((g * 2 + 1) ^ sw) * 4];
            #pragma unroll
            for (int ms = 0; ms < 4; ++ms)
                acc[ms][ns] = __builtin_amdgcn_mfma_f32_16x16x32_bf16(
                    afC[ms], bf, acc[ms][ns], 0, 0, 0);
        }
        __syncthreads();   // drains this tile's wvN/afN issues; publishes Blds
        if (m1) {
            #pragma unroll
            for (int ms = 0; ms < 4; ++ms) afC[ms] = afN[ms];
            #pragma unroll
            for (int i = 0; i < 4; ++i) wvC[i] = wvN[i];
            c ^= 1;
        }
    }

    // epilogue: write split partial
    float* Cp = Cpart + (size_t)s * NROW * DDIM;
    #pragma unroll
    for (int ms = 0; ms < 4; ++ms) {
        const int row = m0 + wr * 64 + ms * 16 + g * 4;
        #pragma unroll
        for (int ns = 0; ns < 2; ++ns) {
            const int col = n0 + wc * 32 + ns * 16 + r15;
            if (col < DDIM) {
                #pragma unroll
                for (int r = 0; r < 4; ++r)
                    Cp[(size_t)(row + r) * DDIM + col] = acc[ms][ns][r];
            }
        }
    }
}

// ---------------------------------------------------------------------------
// Kernel 3: sum S split partials -> C, plus per-row inverse norm.
// ---------------------------------------------------------------------------
__global__ void reduce_norm(const float* __restrict__ Cpart,
                            float* __restrict__ C,
                            float* __restrict__ inv_norm, int S) {
    const int row = blockIdx.x;
    const int tid = threadIdx.x;
    float acc = 0.f;
    for (int c = tid; c < DDIM; c += 256) {
        float v = 0.f;
        for (int s2 = 0; s2 < S; ++s2)
            v += Cpart[((size_t)s2 * NROW + row) * DDIM + c];
        C[(size_t)row * DDIM + c] = v;
        acc += v * v;
    }
    __shared__ float red[4];
    #pragma unroll
    for (int off = 32; off > 0; off >>= 1) acc += __shfl_xor(acc, off);
    if ((tid & 63) == 0) red[tid >> 6] = acc;
    __syncthreads();
    if (tid == 0) {
        float a = red[0] + red[1] + red[2] + red[3];
        inv_norm[row] = 1.f / fmaxf(sqrtf(a), 1e-8f);
    }
}

// ---------------------------------------------------------------------------
// Kernel 4: fused cosine-sim (480x32) + log_softmax. One block per query row.
// ---------------------------------------------------------------------------
__global__ void simlog(const float* __restrict__ C,
                       const float* __restrict__ inv_norm,
                       float* __restrict__ out) {
    __shared__ float qs[DDIM];
    __shared__ float sims[NCLS];
    const int r = blockIdx.x;
    const int tid = threadIdx.x;
    const float* qrow = C + (size_t)(NCLS + r) * DDIM;
    for (int c = tid; c < DDIM; c += 256) qs[c] = qrow[c];
    __syncthreads();
    const float invq = inv_norm[NCLS + r];
    const int lane = tid & 63, w = tid >> 6;
    #pragma unroll
    for (int j = 0; j < 8; ++j) {
        const int p = w * 8 + j;
        const float* prow = C + (size_t)p * DDIM;
        float d = 0.f;
        for (int c = lane; c < DDIM; c += 64) d += qs[c] * prow[c];
        #pragma unroll
        for (int off = 32; off > 0; off >>= 1) d += __shfl_xor(d, off);
        if (lane == 0) sims[p] = d * invq * inv_norm[p];
    }
    __syncthreads();
    if (w == 0) {
        float v = (lane < NCLS) ? sims[lane] : -1e30f;
        float m = v;
        #pragma unroll
        for (int off = 32; off > 0; off >>= 1) m = fmaxf(m, __shfl_xor(m, off));
        float e = (lane < NCLS) ? expf(v - m) : 0.f;
        float ss = e;
        #pragma unroll
        for (int off = 32; off > 0; off >>= 1) ss += __shfl_xor(ss, off);
        if (lane < NCLS) out[(size_t)r * NCLS + lane] = v - m - logf(ss);
    }
}

} // anonymous namespace

// ws layout (bytes):
//   A_bf16 : NROW*KPAD*2   = 21,757,952
//   Cpart  : S*NROW*DDIM*4 = S * 3,276,800   (S=9 -> 29,491,200)
//   C      : NROW*DDIM*4   =  3,276,800
//   invn   : 4,096
// S=9 total ~54.5 MB; S auto-shrinks if ws_size is smaller.

extern "C" void kernel_launch(void* const* d_in, const int* in_sizes, int n_in,
                              void* d_out, int out_size, void* d_ws, size_t ws_size,
                              hipStream_t stream) {
    const float* supp  = (const float*)d_in[0];
    const float* query = (const float*)d_in[1];
    const float* Wenc  = (const float*)d_in[2];
    float* out = (float*)d_out;

    const size_t slot   = (size_t)NROW * DDIM * 4;
    const size_t fixedA = (size_t)NROW * KPAD * 2;
    int S = MAXS;
    if (ws_size) {
        while (S > 1 && fixedA + (size_t)S * slot + slot + 4096 > ws_size) --S;
    }

    char* ws = (char*)d_ws;
    unsigned short* A = (unsigned short*)ws;
    float* Cpart    = (float*)(ws + fixedA);
    float* C        = (float*)(ws + fixedA + (size_t)S * slot);
    float* inv_norm = (float*)(ws + fixedA + (size_t)(S + 1) * slot);

    hipLaunchKernelGGL(prep_A, dim3((KPAD / 4 + 255) / 256, NROW), dim3(256),
                       0, stream, supp, query, A);
    hipLaunchKernelGGL(gemm3, dim3(26 * S), dim3(1024), 0, stream,
                       A, Wenc, Cpart, S);
    hipLaunchKernelGGL(reduce_norm, dim3(NROW), dim3(256), 0, stream,
                       Cpart, C, inv_norm, S);
    hipLaunchKernelGGL(simlog, dim3(NQROW), dim3(256), 0, stream,
                       C, inv_norm, out);
}

// Round 4
// 221.309 us; speedup vs baseline: 1.2134x; 1.2134x over previous
//
#include <hip/hip_runtime.h>
#include <cstdint>
#include <cstddef>

namespace {

constexpr int NCLS   = 32;
constexpr int KSHOT  = 5;
constexpr int FDIM   = 21168;   // 3*84*84
constexpr int KPAD   = 21248;   // 332 * 64
constexpr int DDIM   = 1600;
constexpr int NROW   = 512;     // 32 proto + 480 query
constexpr int NQROW  = 480;
constexpr int NKT    = 332;     // K tiles of 64
constexpr int MAXS   = 14;      // split-K: 52*14 = 728 blocks ~ 2.84/CU

using short8 = __attribute__((ext_vector_type(8))) short;
using f32x4  = __attribute__((ext_vector_type(4))) float;

__device__ __forceinline__ unsigned short f2bf(float x) {
    union { float f; unsigned u; } v; v.f = x;
    unsigned r = v.u + 0x7fffu + ((v.u >> 16) & 1u);   // RNE
    return (unsigned short)(r >> 16);
}

// ---------------------------------------------------------------------------
// Kernel 1: build A_bf16 [512][KPAD]; rows 0..31 = 5-shot mean, rest = query.
// ---------------------------------------------------------------------------
__global__ void prep_A(const float* __restrict__ supp,
                       const float* __restrict__ query,
                       unsigned short* __restrict__ A) {
    const int r = blockIdx.y;
    const int u = blockIdx.x * blockDim.x + threadIdx.x;
    if (u >= KPAD / 4) return;
    const int c = u * 4;
    float4 v = make_float4(0.f, 0.f, 0.f, 0.f);
    if (c < FDIM) {   // FDIM % 4 == 0
        if (r < NCLS) {
            const float* s = supp + (size_t)r * KSHOT * FDIM + c;
            float4 a0 = *(const float4*)(s);
            float4 a1 = *(const float4*)(s + FDIM);
            float4 a2 = *(const float4*)(s + 2 * FDIM);
            float4 a3 = *(const float4*)(s + 3 * FDIM);
            float4 a4 = *(const float4*)(s + 4 * FDIM);
            v.x = (a0.x + a1.x + a2.x + a3.x + a4.x) * 0.2f;
            v.y = (a0.y + a1.y + a2.y + a3.y + a4.y) * 0.2f;
            v.z = (a0.z + a1.z + a2.z + a3.z + a4.z) * 0.2f;
            v.w = (a0.w + a1.w + a2.w + a3.w + a4.w) * 0.2f;
        } else {
            v = *(const float4*)(query + (size_t)(r - NCLS) * FDIM + c);
        }
    }
    ushort4 o;
    o.x = f2bf(v.x); o.y = f2bf(v.y); o.z = f2bf(v.z); o.w = f2bf(v.w);
    *(ushort4*)(A + (size_t)r * KPAD + c) = o;
}

// ---------------------------------------------------------------------------
// Kernel 1b: transpose + convert W fp32 [FDIM][DDIM] -> Wt bf16 [DDIM][KPAD]
// (k-contiguous rows, zero-padded k >= FDIM). 64x64 tiles through LDS.
// ---------------------------------------------------------------------------
__global__ void prep_Wt(const float* __restrict__ W,
                        unsigned short* __restrict__ Wt) {
    __shared__ unsigned short T[64][68];   // [n][k], +4 pad
    const int k0 = blockIdx.x * 64;        // 0..331
    const int n0 = blockIdx.y * 64;        // 0..24
    const int t  = threadIdx.x;            // 256
    const int cr = t >> 4;                 // k row within pass
    const int cc = (t & 15) * 4;           // n col
    #pragma unroll
    for (int p = 0; p < 4; ++p) {
        const int kr = p * 16 + cr;
        const int kg = k0 + kr;
        float4 v = (kg < FDIM)
                 ? *(const float4*)&W[(size_t)kg * DDIM + n0 + cc]
                 : make_float4(0.f, 0.f, 0.f, 0.f);
        T[cc + 0][kr] = f2bf(v.x);
        T[cc + 1][kr] = f2bf(v.y);
        T[cc + 2][kr] = f2bf(v.z);
        T[cc + 3][kr] = f2bf(v.w);
    }
    __syncthreads();
    #pragma unroll
    for (int p = 0; p < 2; ++p) {
        const int nr = p * 32 + (t >> 3);
        const int ks = (t & 7) * 8;
        uint2 lo = *(const uint2*)&T[nr][ks];
        uint2 hi = *(const uint2*)&T[nr][ks + 4];
        *(uint4*)&Wt[(size_t)(n0 + nr) * KPAD + k0 + ks] =
            make_uint4(lo.x, lo.y, hi.x, hi.y);
    }
}

// ---------------------------------------------------------------------------
// Kernel 2: GEMM Cpart[s] = A-tile @ Wt-tile^T.  m97 geometry: BM=BN=128,
// BK=64, 256 threads = 4 waves (2m x 2n), wave tile 64x64, acc 4x4.
// Both operands: global_load_lds 16B, XOR-preswizzled source, linear LDS.
// Simple 2-barrier loop. Split-K over S partial buffers.
// ---------------------------------------------------------------------------
__global__ __launch_bounds__(256, 3) void gemm4(
        const unsigned short* __restrict__ A,    // [512][KPAD]
        const unsigned short* __restrict__ Wt,   // [1600][KPAD]
        float* __restrict__ Cpart, int S) {      // [S][512][DDIM]
    __shared__ unsigned short Al[128 * 64];
    __shared__ unsigned short Bl[128 * 64];

    const int bid = blockIdx.x;
    const int s   = bid / 52;
    const int rem = bid % 52;
    const int mt  = rem / 13;
    const int nt  = rem % 13;
    const int m0  = mt * 128;
    const int n0  = nt * 128;
    const int t0  = (NKT * s) / S;
    const int t1  = (NKT * (s + 1)) / S;

    const int tid  = threadIdx.x;
    const int lane = tid & 63;
    const int w    = tid >> 6;      // 0..3
    const int wr   = w & 1;         // m-half
    const int wc   = w >> 1;        // n-half
    const int r15  = lane & 15;
    const int g    = lane >> 4;     // 0..3
    const int srow = lane >> 3;     // staging row-in-group
    const int sblk = lane & 7;      // staging 16B block

    // precomputed, swizzle folded into source pointers
    const unsigned short* Asrc[4];
    const unsigned short* Bsrc[4];
    unsigned short* Adst[4];
    unsigned short* Bdst[4];
    #pragma unroll
    for (int i = 0; i < 4; ++i) {
        const int r = w * 32 + i * 8 + srow;        // local row 0..127
        const int d = (sblk ^ (r & 7)) * 8;         // preswizzled src offset
        Asrc[i] = A + (size_t)(m0 + r) * KPAD + d;
        const int bn = min(n0 + r, DDIM - 1);       // clamp tail n-tile
        Bsrc[i] = Wt + (size_t)bn * KPAD + d;
        Adst[i] = &Al[(w * 32 + i * 8) * 64];
        Bdst[i] = &Bl[(w * 32 + i * 8) * 64];
    }

    f32x4 acc[4][4];
    #pragma unroll
    for (int i = 0; i < 4; ++i)
        #pragma unroll
        for (int j = 0; j < 4; ++j)
            acc[i][j] = (f32x4){0.f, 0.f, 0.f, 0.f};

    for (int t = t0; t < t1; ++t) {
        const int k0 = t * 64;
        #pragma unroll
        for (int i = 0; i < 4; ++i) {
            __builtin_amdgcn_global_load_lds(
                (const __attribute__((address_space(1))) void*)(Asrc[i] + k0),
                (__attribute__((address_space(3))) void*)Adst[i], 16, 0, 0);
            __builtin_amdgcn_global_load_lds(
                (const __attribute__((address_space(1))) void*)(Bsrc[i] + k0),
                (__attribute__((address_space(3))) void*)Bdst[i], 16, 0, 0);
        }
        __syncthreads();
        #pragma unroll
        for (int kk = 0; kk < 2; ++kk) {
            short8 af[4], bf[4];
            #pragma unroll
            for (int ms = 0; ms < 4; ++ms) {
                const int R = wr * 64 + ms * 16 + r15;
                af[ms] = *(const short8*)&Al[R * 64 + (((kk * 4 + g) ^ (R & 7)) * 8)];
            }
            #pragma unroll
            for (int ns = 0; ns < 4; ++ns) {
                const int Rn = wc * 64 + ns * 16 + r15;
                bf[ns] = *(const short8*)&Bl[Rn * 64 + (((kk * 4 + g) ^ (Rn & 7)) * 8)];
            }
            #pragma unroll
            for (int ms = 0; ms < 4; ++ms)
                #pragma unroll
                for (int ns = 0; ns < 4; ++ns)
                    acc[ms][ns] = __builtin_amdgcn_mfma_f32_16x16x32_bf16(
                        af[ms], bf[ns], acc[ms][ns], 0, 0, 0);
        }
        __syncthreads();
    }

    float* Cp = Cpart + (size_t)s * NROW * DDIM;
    #pragma unroll
    for (int ms = 0; ms < 4; ++ms) {
        const int row = m0 + wr * 64 + ms * 16 + g * 4;
        #pragma unroll
        for (int ns = 0; ns < 4; ++ns) {
            const int col = n0 + wc * 64 + ns * 16 + r15;
            if (col < DDIM) {
                #pragma unroll
                for (int r = 0; r < 4; ++r)
                    Cp[(size_t)(row + r) * DDIM + col] = acc[ms][ns][r];
            }
        }
    }
}

// ---------------------------------------------------------------------------
// Kernel 3: sum S split partials -> C, plus per-row inverse norm.
// ---------------------------------------------------------------------------
__global__ void reduce_norm(const float* __restrict__ Cpart,
                            float* __restrict__ C,
                            float* __restrict__ inv_norm, int S) {
    const int row = blockIdx.x;
    const int tid = threadIdx.x;
    float acc = 0.f;
    for (int c = tid; c < DDIM; c += 256) {
        float v = 0.f;
        for (int s2 = 0; s2 < S; ++s2)
            v += Cpart[((size_t)s2 * NROW + row) * DDIM + c];
        C[(size_t)row * DDIM + c] = v;
        acc += v * v;
    }
    __shared__ float red[4];
    #pragma unroll
    for (int off = 32; off > 0; off >>= 1) acc += __shfl_xor(acc, off);
    if ((tid & 63) == 0) red[tid >> 6] = acc;
    __syncthreads();
    if (tid == 0) {
        float a = red[0] + red[1] + red[2] + red[3];
        inv_norm[row] = 1.f / fmaxf(sqrtf(a), 1e-8f);
    }
}

// ---------------------------------------------------------------------------
// Kernel 4: fused cosine-sim (480x32) + log_softmax. One block per query row.
// ---------------------------------------------------------------------------
__global__ void simlog(const float* __restrict__ C,
                       const float* __restrict__ inv_norm,
                       float* __restrict__ out) {
    __shared__ float qs[DDIM];
    __shared__ float sims[NCLS];
    const int r = blockIdx.x;
    const int tid = threadIdx.x;
    const float* qrow = C + (size_t)(NCLS + r) * DDIM;
    for (int c = tid; c < DDIM; c += 256) qs[c] = qrow[c];
    __syncthreads();
    const float invq = inv_norm[NCLS + r];
    const int lane = tid & 63, w = tid >> 6;
    #pragma unroll
    for (int j = 0; j < 8; ++j) {
        const int p = w * 8 + j;
        const float* prow = C + (size_t)p * DDIM;
        float d = 0.f;
        for (int c = lane; c < DDIM; c += 64) d += qs[c] * prow[c];
        #pragma unroll
        for (int off = 32; off > 0; off >>= 1) d += __shfl_xor(d, off);
        if (lane == 0) sims[p] = d * invq * inv_norm[p];
    }
    __syncthreads();
    if (w == 0) {
        float v = (lane < NCLS) ? sims[lane] : -1e30f;
        float m = v;
        #pragma unroll
        for (int off = 32; off > 0; off >>= 1) m = fmaxf(m, __shfl_xor(m, off));
        float e = (lane < NCLS) ? expf(v - m) : 0.f;
        float ss = e;
        #pragma unroll
        for (int off = 32; off > 0; off >>= 1) ss += __shfl_xor(ss, off);
        if (lane < NCLS) out[(size_t)r * NCLS + lane] = v - m - logf(ss);
    }
}

} // anonymous namespace

// ws layout (bytes):
//   A_bf16 : 512*21248*2  = 21,757,952                     [0, offWt)
//   Wt     : 1600*21248*2 = 67,993,600                     [offWt, offCp)
//   Cpart  : S*512*1600*4 = S*3,276,800                    [offCp, ...)
//   C      : overlays Wt (dead after gemm), 3,276,800
//   invn   : overlays Wt + 3,276,800
// Peak = 89,751,552 + S*3,276,800 (S=14 -> ~135.6 MB), S adapts to ws_size.

extern "C" void kernel_launch(void* const* d_in, const int* in_sizes, int n_in,
                              void* d_out, int out_size, void* d_ws, size_t ws_size,
                              hipStream_t stream) {
    const float* supp  = (const float*)d_in[0];
    const float* query = (const float*)d_in[1];
    const float* Wenc  = (const float*)d_in[2];
    float* out = (float*)d_out;

    const size_t offWt = 21757952;
    const size_t offCp = offWt + 67993600;      // 89,751,552
    const size_t slot  = (size_t)NROW * DDIM * 4;

    int S = MAXS;
    if (ws_size > offCp) {
        size_t avail = (ws_size - offCp) / slot;
        if ((size_t)S > avail) S = (int)avail;
    }
    if (S < 1) S = 1;

    char* ws = (char*)d_ws;
    unsigned short* A  = (unsigned short*)ws;
    unsigned short* Wt = (unsigned short*)(ws + offWt);
    float* Cpart    = (float*)(ws + offCp);
    float* C        = (float*)(ws + offWt);              // overlay (post-gemm)
    float* inv_norm = (float*)(ws + offWt + slot);       // overlay (post-gemm)

    hipLaunchKernelGGL(prep_A, dim3((KPAD / 4 + 255) / 256, NROW), dim3(256),
                       0, stream, supp, query, A);
    hipLaunchKernelGGL(prep_Wt, dim3(KPAD / 64, DDIM / 64), dim3(256),
                       0, stream, Wenc, Wt);
    hipLaunchKernelGGL(gemm4, dim3(52 * S), dim3(256), 0, stream,
                       A, Wt, Cpart, S);
    hipLaunchKernelGGL(reduce_norm, dim3(NROW), dim3(256), 0, stream,
                       Cpart, C, inv_norm, S);
    hipLaunchKernelGGL(simlog, dim3(NQROW), dim3(256), 0, stream,
                       C, inv_norm, out);
}

// Round 5
// 195.790 us; speedup vs baseline: 1.3715x; 1.1303x over previous
//
#include <hip/hip_runtime.h>
#include <cstdint>
#include <cstddef>

namespace {

constexpr int NCLS   = 32;
constexpr int KSHOT  = 5;
constexpr int FDIM   = 21168;   // 3*84*84
constexpr int KPAD   = 21248;   // 664 * 32
constexpr int DDIM   = 1600;    // 25 * 64
constexpr int NROW   = 512;     // 32 proto + 480 query
constexpr int NQROW  = 480;
constexpr int NKT32  = 664;     // K tiles of 32
constexpr int MAXS   = 15;      // grid = 50*15 = 750 ~ 2.93 blocks/CU

using short8 = __attribute__((ext_vector_type(8))) short;
using f32x4  = __attribute__((ext_vector_type(4))) float;

__device__ __forceinline__ unsigned f2bf(float x) {
    union { float f; unsigned u; } v; v.f = x;
    unsigned r = v.u + 0x7fffu + ((v.u >> 16) & 1u);   // RNE
    return r >> 16;
}

// ---------------------------------------------------------------------------
// Kernel 1: build A_bf16 [512][KPAD]; rows 0..31 = 5-shot mean, rest = query.
// ---------------------------------------------------------------------------
__global__ void prep_A(const float* __restrict__ supp,
                       const float* __restrict__ query,
                       unsigned short* __restrict__ A) {
    const int r = blockIdx.y;
    const int u = blockIdx.x * blockDim.x + threadIdx.x;
    if (u >= KPAD / 4) return;
    const int c = u * 4;
    float4 v = make_float4(0.f, 0.f, 0.f, 0.f);
    if (c < FDIM) {   // FDIM % 4 == 0
        if (r < NCLS) {
            const float* s = supp + (size_t)r * KSHOT * FDIM + c;
            float4 a0 = *(const float4*)(s);
            float4 a1 = *(const float4*)(s + FDIM);
            float4 a2 = *(const float4*)(s + 2 * FDIM);
            float4 a3 = *(const float4*)(s + 3 * FDIM);
            float4 a4 = *(const float4*)(s + 4 * FDIM);
            v.x = (a0.x + a1.x + a2.x + a3.x + a4.x) * 0.2f;
            v.y = (a0.y + a1.y + a2.y + a3.y + a4.y) * 0.2f;
            v.z = (a0.z + a1.z + a2.z + a3.z + a4.z) * 0.2f;
            v.w = (a0.w + a1.w + a2.w + a3.w + a4.w) * 0.2f;
        } else {
            v = *(const float4*)(query + (size_t)(r - NCLS) * FDIM + c);
        }
    }
    ushort4 o;
    o.x = (unsigned short)f2bf(v.x); o.y = (unsigned short)f2bf(v.y);
    o.z = (unsigned short)f2bf(v.z); o.w = (unsigned short)f2bf(v.w);
    *(ushort4*)(A + (size_t)r * KPAD + c) = o;
}

// ---------------------------------------------------------------------------
// Kernel 2: fused GEMM, W consumed fp32 directly (no transpose prepass).
// BM=256 (4 waves m-stacked, wave-tile 64x64), BN=64, BK=32, 256 threads.
// A: per-wave-exclusive rows, global->reg fragments, depth-1 prefetch.
// W: 8 coalesced fp32 scalar loads/thread, depth-1 reg prefetch, packed to
// bf16 and written via one ds_write_b128 into a double-buffered 4 KB LDS
// tile with slot-XOR swizzle. One barrier per K-tile.
// ---------------------------------------------------------------------------
__global__ __launch_bounds__(256, 3) void gemm5(
        const unsigned short* __restrict__ A,    // [512][KPAD] bf16 bits
        const float* __restrict__ W,             // [FDIM][DDIM] fp32
        float* __restrict__ Cpart, int S) {      // [S][512][DDIM]
    __shared__ unsigned short Bl[2][64 * 32];    // [n][k] swizzled, 4 KB each

    const int bid = blockIdx.x;
    const int s   = bid / 50;
    const int rem = bid % 50;
    const int mt  = rem / 25;
    const int nt  = rem % 25;
    const int m0  = mt * 256;
    const int n0  = nt * 64;
    const int t0  = (NKT32 * s) / S;
    const int t1  = (NKT32 * (s + 1)) / S;

    const int tid  = threadIdx.x;
    const int lane = tid & 63;
    const int wid  = tid >> 6;      // 0..3 (m-wave; also W k-quad role)
    const int g    = lane >> 4;     // 0..3
    const int r15  = lane & 15;

    // W staging role: bn = column 0..63, kq = 8-k group 0..3
    const int bn = tid & 63;
    const int kq = tid >> 6;
    const float* Wp = W + n0 + bn;
    const int waddr = bn * 32 + ((kq ^ ((bn >> 1) & 3)) * 8);  // shorts

    // per-lane A fragment pointers (wave-exclusive rows)
    const unsigned short* Arow[4];
    #pragma unroll
    for (int ms = 0; ms < 4; ++ms)
        Arow[ms] = A + (size_t)(m0 + wid * 64 + ms * 16 + r15) * KPAD + g * 8;

    f32x4 acc[4][4];
    #pragma unroll
    for (int i = 0; i < 4; ++i)
        #pragma unroll
        for (int j = 0; j < 4; ++j)
            acc[i][j] = (f32x4){0.f, 0.f, 0.f, 0.f};

    float wvC[8], wvN[8];
    short8 afC[4], afN[4];

    // ---- prologue: stage B(t0); preload wvC=W(t0+1), afC=A(t0) ----
    {
        const int kb = t0 * 32 + kq * 8;
        float w0[8];
        #pragma unroll
        for (int i = 0; i < 8; ++i)
            w0[i] = (kb + i < FDIM) ? Wp[(size_t)(kb + i) * DDIM] : 0.f;
        uint4 p;
        p.x = f2bf(w0[0]) | (f2bf(w0[1]) << 16);
        p.y = f2bf(w0[2]) | (f2bf(w0[3]) << 16);
        p.z = f2bf(w0[4]) | (f2bf(w0[5]) << 16);
        p.w = f2bf(w0[6]) | (f2bf(w0[7]) << 16);
        *(uint4*)&Bl[0][waddr] = p;
    }
    if (t0 + 1 < t1) {
        const int kb = (t0 + 1) * 32 + kq * 8;
        #pragma unroll
        for (int i = 0; i < 8; ++i)
            wvC[i] = (kb + i < FDIM) ? Wp[(size_t)(kb + i) * DDIM] : 0.f;
    }
    #pragma unroll
    for (int ms = 0; ms < 4; ++ms)
        afC[ms] = *(const short8*)(Arow[ms] + t0 * 32);
    __syncthreads();

    int cur = 0;
    for (int t = t0; t < t1; ++t) {
        const bool m1 = (t + 1 < t1);
        const bool m2 = (t + 2 < t1);
        // issue next A fragments and next-next W loads first
        if (m1) {
            #pragma unroll
            for (int ms = 0; ms < 4; ++ms)
                afN[ms] = *(const short8*)(Arow[ms] + (t + 1) * 32);
        }
        if (m2) {
            const int kb = (t + 2) * 32 + kq * 8;
            #pragma unroll
            for (int i = 0; i < 8; ++i)
                wvN[i] = (kb + i < FDIM) ? Wp[(size_t)(kb + i) * DDIM] : 0.f;
        }
        // pack wvC (arrived: issued last tile) -> other LDS buffer
        if (m1) {
            uint4 p;
            p.x = f2bf(wvC[0]) | (f2bf(wvC[1]) << 16);
            p.y = f2bf(wvC[2]) | (f2bf(wvC[3]) << 16);
            p.z = f2bf(wvC[4]) | (f2bf(wvC[5]) << 16);
            p.w = f2bf(wvC[6]) | (f2bf(wvC[7]) << 16);
            *(uint4*)&Bl[cur ^ 1][waddr] = p;
        }
        // compute on Bl[cur] with afC
        short8 bf[4];
        #pragma unroll
        for (int ns = 0; ns < 4; ++ns) {
            const int n = ns * 16 + r15;
            bf[ns] = *(const short8*)&Bl[cur][n * 32 + ((g ^ ((n >> 1) & 3)) * 8)];
        }
        #pragma unroll
        for (int ms = 0; ms < 4; ++ms)
            #pragma unroll
            for (int ns = 0; ns < 4; ++ns)
                acc[ms][ns] = __builtin_amdgcn_mfma_f32_16x16x32_bf16(
                    afC[ms], bf[ns], acc[ms][ns], 0, 0, 0);
        __syncthreads();
        if (m1) {
            #pragma unroll
            for (int ms = 0; ms < 4; ++ms) afC[ms] = afN[ms];
            #pragma unroll
            for (int i = 0; i < 8; ++i) wvC[i] = wvN[i];
            cur ^= 1;
        }
    }

    // epilogue: write split partial (no guards: 512 % 256 == 0, 1600 % 64 == 0)
    float* Cp = Cpart + (size_t)s * NROW * DDIM;
    #pragma unroll
    for (int ms = 0; ms < 4; ++ms) {
        const int row = m0 + wid * 64 + ms * 16 + g * 4;
        #pragma unroll
        for (int ns = 0; ns < 4; ++ns) {
            const int col = n0 + ns * 16 + r15;
            #pragma unroll
            for (int r = 0; r < 4; ++r)
                Cp[(size_t)(row + r) * DDIM + col] = acc[ms][ns][r];
        }
    }
}

// ---------------------------------------------------------------------------
// Kernel 3: sum S split partials -> C, plus per-row inverse norm.
// ---------------------------------------------------------------------------
__global__ void reduce_norm(const float* __restrict__ Cpart,
                            float* __restrict__ C,
                            float* __restrict__ inv_norm, int S) {
    const int row = blockIdx.x;
    const int tid = threadIdx.x;
    float acc = 0.f;
    for (int c = tid; c < DDIM; c += 256) {
        float v = 0.f;
        for (int s2 = 0; s2 < S; ++s2)
            v += Cpart[((size_t)s2 * NROW + row) * DDIM + c];
        C[(size_t)row * DDIM + c] = v;
        acc += v * v;
    }
    __shared__ float red[4];
    #pragma unroll
    for (int off = 32; off > 0; off >>= 1) acc += __shfl_xor(acc, off);
    if ((tid & 63) == 0) red[tid >> 6] = acc;
    __syncthreads();
    if (tid == 0) {
        float a = red[0] + red[1] + red[2] + red[3];
        inv_norm[row] = 1.f / fmaxf(sqrtf(a), 1e-8f);
    }
}

// ---------------------------------------------------------------------------
// Kernel 4: fused cosine-sim (480x32) + log_softmax. One block per query row.
// ---------------------------------------------------------------------------
__global__ void simlog(const float* __restrict__ C,
                       const float* __restrict__ inv_norm,
                       float* __restrict__ out) {
    __shared__ float qs[DDIM];
    __shared__ float sims[NCLS];
    const int r = blockIdx.x;
    const int tid = threadIdx.x;
    const float* qrow = C + (size_t)(NCLS + r) * DDIM;
    for (int c = tid; c < DDIM; c += 256) qs[c] = qrow[c];
    __syncthreads();
    const float invq = inv_norm[NCLS + r];
    const int lane = tid & 63, w = tid >> 6;
    #pragma unroll
    for (int j = 0; j < 8; ++j) {
        const int p = w * 8 + j;
        const float* prow = C + (size_t)p * DDIM;
        float d = 0.f;
        for (int c = lane; c < DDIM; c += 64) d += qs[c] * prow[c];
        #pragma unroll
        for (int off = 32; off > 0; off >>= 1) d += __shfl_xor(d, off);
        if (lane == 0) sims[p] = d * invq * inv_norm[p];
    }
    __syncthreads();
    if (w == 0) {
        float v = (lane < NCLS) ? sims[lane] : -1e30f;
        float m = v;
        #pragma unroll
        for (int off = 32; off > 0; off >>= 1) m = fmaxf(m, __shfl_xor(m, off));
        float e = (lane < NCLS) ? expf(v - m) : 0.f;
        float ss = e;
        #pragma unroll
        for (int off = 32; off > 0; off >>= 1) ss += __shfl_xor(ss, off);
        if (lane < NCLS) out[(size_t)r * NCLS + lane] = v - m - logf(ss);
    }
}

} // anonymous namespace

// ws layout (bytes):
//   A_bf16 : 512*21248*2  = 21,757,952
//   Cpart  : S*512*1600*4 = S*3,276,800   (S=15 -> 49,152,000)
//   C      : 3,276,800
//   invn   : 4,096
// S=15 total ~74.2 MB; S auto-shrinks if ws_size is smaller.

extern "C" void kernel_launch(void* const* d_in, const int* in_sizes, int n_in,
                              void* d_out, int out_size, void* d_ws, size_t ws_size,
                              hipStream_t stream) {
    const float* supp  = (const float*)d_in[0];
    const float* query = (const float*)d_in[1];
    const float* Wenc  = (const float*)d_in[2];
    float* out = (float*)d_out;

    const size_t fixedA = 21757952;
    const size_t slot   = (size_t)NROW * DDIM * 4;

    int S = MAXS;
    if (ws_size > fixedA + slot + 4096) {
        size_t avail = (ws_size - fixedA - slot - 4096) / slot;
        if ((size_t)S > avail) S = (int)avail;
    }
    if (S < 1) S = 1;

    char* ws = (char*)d_ws;
    unsigned short* A = (unsigned short*)ws;
    float* Cpart    = (float*)(ws + fixedA);
    float* C        = (float*)(ws + fixedA + (size_t)S * slot);
    float* inv_norm = (float*)(ws + fixedA + (size_t)(S + 1) * slot);

    hipLaunchKernelGGL(prep_A, dim3((KPAD / 4 + 255) / 256, NROW), dim3(256),
                       0, stream, supp, query, A);
    hipLaunchKernelGGL(gemm5, dim3(50 * S), dim3(256), 0, stream,
                       A, Wenc, Cpart, S);
    hipLaunchKernelGGL(reduce_norm, dim3(NROW), dim3(256), 0, stream,
                       Cpart, C, inv_norm, S);
    hipLaunchKernelGGL(simlog, dim3(NQROW), dim3(256), 0, stream,
                       C, inv_norm, out);
}

// Round 6
// 181.753 us; speedup vs baseline: 1.4775x; 1.0772x over previous
//
#include <hip/hip_runtime.h>
#include <cstdint>
#include <cstddef>

namespace {

constexpr int NCLS   = 32;
constexpr int KSHOT  = 5;
constexpr int FDIM   = 21168;   // 3*84*84
constexpr int KPAD   = 21248;   // 332 * 64
constexpr int DDIM   = 1600;
constexpr int NROW   = 512;     // 32 proto + 480 query
constexpr int NQROW  = 480;
constexpr int NKT    = 332;     // K tiles of 64
constexpr int MAXS   = 19;      // grid = 26*19 = 494 ~ 1.93 blocks/CU

using short8 = __attribute__((ext_vector_type(8))) short;
using f32x4  = __attribute__((ext_vector_type(4))) float;

__device__ __forceinline__ unsigned f2bf(float x) {
    union { float f; unsigned u; } v; v.f = x;
    unsigned r = v.u + 0x7fffu + ((v.u >> 16) & 1u);   // RNE
    return r >> 16;
}

// ---------------------------------------------------------------------------
// Kernel 1: build A_bf16 [512][KPAD]; rows 0..31 = 5-shot mean, rest = query.
// ---------------------------------------------------------------------------
__global__ void prep_A(const float* __restrict__ supp,
                       const float* __restrict__ query,
                       unsigned short* __restrict__ A) {
    const int r = blockIdx.y;
    const int u = blockIdx.x * blockDim.x + threadIdx.x;
    if (u >= KPAD / 4) return;
    const int c = u * 4;
    float4 v = make_float4(0.f, 0.f, 0.f, 0.f);
    if (c < FDIM) {   // FDIM % 4 == 0
        if (r < NCLS) {
            const float* s = supp + (size_t)r * KSHOT * FDIM + c;
            float4 a0 = *(const float4*)(s);
            float4 a1 = *(const float4*)(s + FDIM);
            float4 a2 = *(const float4*)(s + 2 * FDIM);
            float4 a3 = *(const float4*)(s + 3 * FDIM);
            float4 a4 = *(const float4*)(s + 4 * FDIM);
            v.x = (a0.x + a1.x + a2.x + a3.x + a4.x) * 0.2f;
            v.y = (a0.y + a1.y + a2.y + a3.y + a4.y) * 0.2f;
            v.z = (a0.z + a1.z + a2.z + a3.z + a4.z) * 0.2f;
            v.w = (a0.w + a1.w + a2.w + a3.w + a4.w) * 0.2f;
        } else {
            v = *(const float4*)(query + (size_t)(r - NCLS) * FDIM + c);
        }
    }
    ushort4 o;
    o.x = (unsigned short)f2bf(v.x); o.y = (unsigned short)f2bf(v.y);
    o.z = (unsigned short)f2bf(v.z); o.w = (unsigned short)f2bf(v.w);
    *(ushort4*)(A + (size_t)r * KPAD + c) = o;
}

// ---------------------------------------------------------------------------
// Kernel 2: GEMM with in-kernel W transpose+convert.
// BM=256, BN=128, BK=64, 512 threads = 8 waves (4m x 2n), wave tile 64x64.
// A: bf16, global_load_lds 16B with XOR-preswizzled source (gemm4 core).
// W: 8x coalesced float2 (512B bursts), k-pairs packed to u32 in regs, one
//    ds_write_b128 quad per column into 9-quad padded rows with quad-XOR
//    (q ^ ((n>>3)&7)) -- both write and b128 frag-read are bank-optimal.
// Pipeline: W(t+1) issued at top of compute segment (drains at b1);
// glds A(t+1) + pack(t+1) in segment 2 (drain at b2). 2 barriers/tile.
// ---------------------------------------------------------------------------
__global__ __launch_bounds__(512, 4) void gemm6(
        const unsigned short* __restrict__ A,    // [512][KPAD] bf16 bits
        const float* __restrict__ W,             // [FDIM][DDIM] fp32
        float* __restrict__ Cpart, int S) {      // [S][512][DDIM]
    __shared__ unsigned short Al[256 * 64];      // 32 KB, XOR-content layout
    __shared__ uint4 Bq[128 * 9];                // 18 KB, 8 data + 1 pad quads/row

    const int bid = blockIdx.x;
    const int mt  = bid & 1;
    const int nt  = (bid >> 1) % 13;
    const int s   = bid / 26;
    const int m0  = mt * 256;
    const int n0  = nt * 128;
    const int t0  = (NKT * s) / S;
    const int t1  = (NKT * (s + 1)) / S;

    const int tid  = threadIdx.x;
    const int lane = tid & 63;
    const int w    = tid >> 6;      // 0..7
    const int wr   = w & 3;         // m-wave 0..3
    const int wc   = w >> 2;        // n-wave 0..1
    const int g    = lane >> 4;     // 0..3
    const int r15  = lane & 15;

    // ---- A staging roles (gemm4 pattern, preswizzled source) ----
    const int srow = lane >> 3;     // 0..7
    const int sblk = lane & 7;
    const unsigned short* Asrc[4];
    unsigned short* Adst[4];
    #pragma unroll
    for (int i = 0; i < 4; ++i) {
        const int r = w * 32 + i * 8 + srow;       // local row 0..255
        Asrc[i] = A + (size_t)(m0 + r) * KPAD + (size_t)((sblk ^ (r & 7)) * 8);
        Adst[i] = &Al[(w * 32 + i * 8) * 64];
    }

    // ---- W staging roles: n-pair = (tid&63)*2, k-octet = tid>>6 ----
    const int n2 = (tid & 63) * 2;
    const int kh = tid >> 6;        // 0..7
    const int wcol = min(n0 + n2, DDIM - 2);       // float2-safe clamp
    const float* Wp = W + wcol;
    // destination quads for the two columns
    const int q0 = (n2 + 0) * 9 + (kh ^ (((n2 + 0) >> 3) & 7));
    const int q1 = (n2 + 1) * 9 + (kh ^ (((n2 + 1) >> 3) & 7));

    f32x4 acc[4][4];
    #pragma unroll
    for (int i = 0; i < 4; ++i)
        #pragma unroll
        for (int j = 0; j < 4; ++j)
            acc[i][j] = (f32x4){0.f, 0.f, 0.f, 0.f};

    float2 wv[8];

    // ---- prologue: W(t0)->wv, glds A(t0), pack->Bq, barrier ----
    #pragma unroll
    for (int i = 0; i < 8; ++i) {
        const int kg = min(t0 * 64 + kh * 8 + i, FDIM - 1);
        wv[i] = *(const float2*)(Wp + (size_t)kg * DDIM);
    }
    #pragma unroll
    for (int i = 0; i < 4; ++i)
        __builtin_amdgcn_global_load_lds(
            (const __attribute__((address_space(1))) void*)(Asrc[i] + t0 * 64),
            (__attribute__((address_space(3))) void*)Adst[i], 16, 0, 0);
    {
        uint4 P0, P1;
        P0.x = f2bf(wv[0].x) | (f2bf(wv[1].x) << 16);
        P0.y = f2bf(wv[2].x) | (f2bf(wv[3].x) << 16);
        P0.z = f2bf(wv[4].x) | (f2bf(wv[5].x) << 16);
        P0.w = f2bf(wv[6].x) | (f2bf(wv[7].x) << 16);
        P1.x = f2bf(wv[0].y) | (f2bf(wv[1].y) << 16);
        P1.y = f2bf(wv[2].y) | (f2bf(wv[3].y) << 16);
        P1.z = f2bf(wv[4].y) | (f2bf(wv[5].y) << 16);
        P1.w = f2bf(wv[6].y) | (f2bf(wv[7].y) << 16);
        Bq[q0] = P0;
        Bq[q1] = P1;
    }
    __syncthreads();

    for (int t = t0; t < t1; ++t) {
        const bool more = (t + 1 < t1);
        // ---- segment 1: issue W(t+1); frag reads + MFMA on tile t ----
        if (more) {
            #pragma unroll
            for (int i = 0; i < 8; ++i) {
                const int kg = min((t + 1) * 64 + kh * 8 + i, FDIM - 1);
                wv[i] = *(const float2*)(Wp + (size_t)kg * DDIM);
            }
        }
        #pragma unroll
        for (int kk = 0; kk < 2; ++kk) {
            const int q = kk * 4 + g;
            short8 bf[4];
            #pragma unroll
            for (int ns = 0; ns < 4; ++ns) {
                const int n = wc * 64 + ns * 16 + r15;
                bf[ns] = *(const short8*)&Bq[n * 9 + (q ^ ((n >> 3) & 7))];
            }
            #pragma unroll
            for (int ms = 0; ms < 4; ++ms) {
                const int R = wr * 64 + ms * 16 + r15;
                short8 af = *(const short8*)&Al[R * 64 + ((q ^ (R & 7)) * 8)];
                #pragma unroll
                for (int ns = 0; ns < 4; ++ns)
                    acc[ms][ns] = __builtin_amdgcn_mfma_f32_16x16x32_bf16(
                        af, bf[ns], acc[ms][ns], 0, 0, 0);
            }
        }
        __syncthreads();   // b1: frag reads done; wv(t+1) drained (long window)

        // ---- segment 2: glds A(t+1), pack wv -> Bq ----
        if (more) {
            #pragma unroll
            for (int i = 0; i < 4; ++i)
                __builtin_amdgcn_global_load_lds(
                    (const __attribute__((address_space(1))) void*)(Asrc[i] + (t + 1) * 64),
                    (__attribute__((address_space(3))) void*)Adst[i], 16, 0, 0);
            uint4 P0, P1;
            P0.x = f2bf(wv[0].x) | (f2bf(wv[1].x) << 16);
            P0.y = f2bf(wv[2].x) | (f2bf(wv[3].x) << 16);
            P0.z = f2bf(wv[4].x) | (f2bf(wv[5].x) << 16);
            P0.w = f2bf(wv[6].x) | (f2bf(wv[7].x) << 16);
            P1.x = f2bf(wv[0].y) | (f2bf(wv[1].y) << 16);
            P1.y = f2bf(wv[2].y) | (f2bf(wv[3].y) << 16);
            P1.z = f2bf(wv[4].y) | (f2bf(wv[5].y) << 16);
            P1.w = f2bf(wv[6].y) | (f2bf(wv[7].y) << 16);
            Bq[q0] = P0;
            Bq[q1] = P1;
        }
        __syncthreads();   // b2: glds + ds_writes drained
    }

    // ---- epilogue: write split partial ----
    float* Cp = Cpart + (size_t)s * NROW * DDIM;
    #pragma unroll
    for (int ms = 0; ms < 4; ++ms) {
        const int row = m0 + wr * 64 + ms * 16 + g * 4;
        #pragma unroll
        for (int ns = 0; ns < 4; ++ns) {
            const int col = n0 + wc * 64 + ns * 16 + r15;
            if (col < DDIM) {
                #pragma unroll
                for (int r = 0; r < 4; ++r)
                    Cp[(size_t)(row + r) * DDIM + col] = acc[ms][ns][r];
            }
        }
    }
}

// ---------------------------------------------------------------------------
// Kernel 3: sum S split partials -> C, plus per-row inverse norm.
// ---------------------------------------------------------------------------
__global__ void reduce_norm(const float* __restrict__ Cpart,
                            float* __restrict__ C,
                            float* __restrict__ inv_norm, int S) {
    const int row = blockIdx.x;
    const int tid = threadIdx.x;
    float acc = 0.f;
    for (int c = tid; c < DDIM; c += 256) {
        float v = 0.f;
        for (int s2 = 0; s2 < S; ++s2)
            v += Cpart[((size_t)s2 * NROW + row) * DDIM + c];
        C[(size_t)row * DDIM + c] = v;
        acc += v * v;
    }
    __shared__ float red[4];
    #pragma unroll
    for (int off = 32; off > 0; off >>= 1) acc += __shfl_xor(acc, off);
    if ((tid & 63) == 0) red[tid >> 6] = acc;
    __syncthreads();
    if (tid == 0) {
        float a = red[0] + red[1] + red[2] + red[3];
        inv_norm[row] = 1.f / fmaxf(sqrtf(a), 1e-8f);
    }
}

// ---------------------------------------------------------------------------
// Kernel 4: fused cosine-sim (480x32) + log_softmax. One block per query row.
// ---------------------------------------------------------------------------
__global__ void simlog(const float* __restrict__ C,
                       const float* __restrict__ inv_norm,
                       float* __restrict__ out) {
    __shared__ float qs[DDIM];
    __shared__ float sims[NCLS];
    const int r = blockIdx.x;
    const int tid = threadIdx.x;
    const float* qrow = C + (size_t)(NCLS + r) * DDIM;
    for (int c = tid; c < DDIM; c += 256) qs[c] = qrow[c];
    __syncthreads();
    const float invq = inv_norm[NCLS + r];
    const int lane = tid & 63, w = tid >> 6;
    #pragma unroll
    for (int j = 0; j < 8; ++j) {
        const int p = w * 8 + j;
        const float* prow = C + (size_t)p * DDIM;
        float d = 0.f;
        for (int c = lane; c < DDIM; c += 64) d += qs[c] * prow[c];
        #pragma unroll
        for (int off = 32; off > 0; off >>= 1) d += __shfl_xor(d, off);
        if (lane == 0) sims[p] = d * invq * inv_norm[p];
    }
    __syncthreads();
    if (w == 0) {
        float v = (lane < NCLS) ? sims[lane] : -1e30f;
        float m = v;
        #pragma unroll
        for (int off = 32; off > 0; off >>= 1) m = fmaxf(m, __shfl_xor(m, off));
        float e = (lane < NCLS) ? expf(v - m) : 0.f;
        float ss = e;
        #pragma unroll
        for (int off = 32; off > 0; off >>= 1) ss += __shfl_xor(ss, off);
        if (lane < NCLS) out[(size_t)r * NCLS + lane] = v - m - logf(ss);
    }
}

} // anonymous namespace

// ws layout (bytes):
//   A_bf16 : 512*21248*2  = 21,757,952
//   Cpart  : S*512*1600*4 = S*3,276,800   (S=19 -> 62,259,200)
//   C      : 3,276,800
//   invn   : 4,096
// S=19 total ~87.3 MB; S auto-shrinks if ws_size is smaller.

extern "C" void kernel_launch(void* const* d_in, const int* in_sizes, int n_in,
                              void* d_out, int out_size, void* d_ws, size_t ws_size,
                              hipStream_t stream) {
    const float* supp  = (const float*)d_in[0];
    const float* query = (const float*)d_in[1];
    const float* Wenc  = (const float*)d_in[2];
    float* out = (float*)d_out;

    const size_t fixedA = 21757952;
    const size_t slot   = (size_t)NROW * DDIM * 4;

    int S = MAXS;
    if (ws_size > fixedA + slot + 4096) {
        size_t avail = (ws_size - fixedA - slot - 4096) / slot;
        if ((size_t)S > avail) S = (int)avail;
    }
    if (S < 1) S = 1;

    char* ws = (char*)d_ws;
    unsigned short* A = (unsigned short*)ws;
    float* Cpart    = (float*)(ws + fixedA);
    float* C        = (float*)(ws + fixedA + (size_t)S * slot);
    float* inv_norm = (float*)(ws + fixedA + (size_t)(S + 1) * slot);

    hipLaunchKernelGGL(prep_A, dim3((KPAD / 4 + 255) / 256, NROW), dim3(256),
                       0, stream, supp, query, A);
    hipLaunchKernelGGL(gemm6, dim3(26 * S), dim3(512), 0, stream,
                       A, Wenc, Cpart, S);
    hipLaunchKernelGGL(reduce_norm, dim3(NROW), dim3(256), 0, stream,
                       Cpart, C, inv_norm, S);
    hipLaunchKernelGGL(simlog, dim3(NQROW), dim3(256), 0, stream,
                       C, inv_norm, out);
}